// Round 16
// baseline (200.902 us; speedup 1.0000x reference)
//
#include <hip/hip_runtime.h>
#include <math.h>

#define NN 20000      // nodes
#define NE 320000     // edges (without self loops)
#define NT 340000     // edges + self loops
#define NG 64         // graphs
#define HB 1329       // (NT+255)/256 hist/scatter blocks
#define CB 8          // W2->bf16 LDS-transpose blocks (512/64)
#define AB 2          // a2p GEMV blocks

using short8  = __attribute__((ext_vector_type(8))) short;   // 8 x bf16 (4 VGPRs)
using float4v = __attribute__((ext_vector_type(4))) float;   // MFMA accumulator

__device__ __forceinline__ float lrelu(float v) { return v > 0.f ? v : 0.2f * v; }
__device__ __forceinline__ float elu1(float v)  { return v > 0.f ? v : (expf(v) - 1.f); }
__device__ __forceinline__ float bflo(unsigned u) { return __uint_as_float(u << 16); }
__device__ __forceinline__ float bfhi(unsigned u) { return __uint_as_float(u & 0xFFFF0000u); }
__device__ __forceinline__ unsigned short f2bf(float f) {
    unsigned u = __float_as_uint(f);
    u += 0x7FFFu + ((u >> 16) & 1u);   // round to nearest even
    return (unsigned short)(u >> 16);
}
__device__ __forceinline__ float bf2f(unsigned short s) {
    return __uint_as_float(((unsigned)s) << 16);
}

#define ACC8(A, ex, hv) \
    A[0] = fmaf(ex, bflo(hv.x), A[0]); \
    A[1] = fmaf(ex, bfhi(hv.x), A[1]); \
    A[2] = fmaf(ex, bflo(hv.y), A[2]); \
    A[3] = fmaf(ex, bfhi(hv.y), A[3]); \
    A[4] = fmaf(ex, bflo(hv.z), A[4]); \
    A[5] = fmaf(ex, bfhi(hv.z), A[5]); \
    A[6] = fmaf(ex, bflo(hv.w), A[6]); \
    A[7] = fmaf(ex, bfhi(hv.w), A[7]);

__device__ __forceinline__ int esrc(const int* ei, int e) { return e < NE ? ei[e] : (e - NE); }
__device__ __forceinline__ int edst(const int* ei, int e) { return e < NE ? ei[NE + e] : (e - NE); }

// ---------- D1: fused prep (all grid-parallel; no serial tail) ----------
__global__ void k_prep(const int* __restrict__ ei, int* __restrict__ deg,
                       const float* __restrict__ W2, unsigned short* __restrict__ W2bfT,
                       const float* __restrict__ as2, const float* __restrict__ ad2,
                       float* __restrict__ a2ps, float* __restrict__ a2pd,
                       const float* __restrict__ x, const float* __restrict__ W1,
                       const float* __restrict__ as1, const float* __restrict__ ad1,
                       unsigned short* __restrict__ h1bf, float* __restrict__ al_s,
                       float* __restrict__ al_d) {
    int tid = threadIdx.x;
    int b = blockIdx.x;
    if (b < HB) {
        int t = b * 256 + tid;
        if (t < NE) atomicAdd(&deg[ei[NE + t]], 1);
        return;
    }
    if (b < HB + CB) {
        // coalesced W2 transpose via LDS tile: 64 k-rows x 64 n-cols
        __shared__ unsigned short tile[64][65];
        int n0t = (b - HB) * 64;
#pragma unroll
        for (int r = 0; r < 16; ++r) {
            int k = r * 4 + (tid >> 6);
            int nl = tid & 63;
            tile[k][nl] = f2bf(W2[k * 512 + n0t + nl]);
        }
        __syncthreads();
#pragma unroll
        for (int r = 0; r < 16; ++r) {
            int nl = r * 4 + (tid >> 6);
            int k = tid & 63;
            W2bfT[(n0t + nl) * 64 + k] = tile[k][nl];
        }
        return;
    }
    if (b < HB + CB + AB) {
        // a2p[k] = sum_j W2[k][j] * a[j]   (64x512 GEMV)
        __shared__ float pp[4][64];
        const float* av = (b == HB + CB) ? as2 : ad2;
        float* outp     = (b == HB + CB) ? a2ps : a2pd;
        int k = tid & 63, seg = tid >> 6;
        float s = 0.f;
        for (int j = seg * 128; j < seg * 128 + 128; ++j)
            s = fmaf(W2[k * 512 + j], av[j], s);
        pp[seg][k] = s;
        __syncthreads();
        if (tid < 64) outp[tid] = pp[0][tid] + pp[1][tid] + pp[2][tid] + pp[3][tid];
        return;
    }
    int n = (b - HB - CB - AB) * 4 + (tid >> 6);
    int j = tid & 63;
    float x0 = x[n * 3 + 0], x1 = x[n * 3 + 1], x2 = x[n * 3 + 2];
    float v = fmaf(x0, W1[j], fmaf(x1, W1[64 + j], x2 * W1[128 + j]));
    h1bf[n * 64 + j] = f2bf(v);
    float ps = v * as1[j];
    float pd = v * ad1[j];
    for (int o = 4; o >= 1; o >>= 1) {
        ps += __shfl_xor(ps, o, 8);
        pd += __shfl_xor(pd, o, 8);
    }
    if ((j & 7) == 0) {
        al_s[n * 8 + (j >> 3)] = ps;
        al_d[n * 8 + (j >> 3)] = pd;
    }
}

// ---------- D2: single-block scan (plain cached loads, L2-hot) + sums zeroing ----------
__global__ void k_scan(const int* __restrict__ deg, const int* __restrict__ batch,
                       int* __restrict__ rowstart, int* __restrict__ cursor,
                       int* __restrict__ gstart, float* __restrict__ sums) {
    __shared__ int part[1024];
    int t = threadIdx.x;
    // zero sums (32768 floats; 8 float4 per thread)
    {
        float4* sp = (float4*)sums;
#pragma unroll
        for (int i = 0; i < 8; ++i)
            sp[t * 8 + i] = make_float4(0.f, 0.f, 0.f, 0.f);
    }
    int base = t * 20;
    int local[20];
    int s = 0;
    if (base < NN) {
#pragma unroll
        for (int i = 0; i < 20; ++i) { local[i] = deg[base + i] + 1; s += local[i]; }
    }
    part[t] = s;
    __syncthreads();
    for (int o = 1; o < 1024; o <<= 1) {
        int v = (t >= o) ? part[t - o] : 0;
        __syncthreads();
        part[t] += v;
        __syncthreads();
    }
    if (base < NN) {
        int run = (t == 0) ? 0 : part[t - 1];
#pragma unroll
        for (int i = 0; i < 20; ++i) {
            rowstart[base + i] = run;
            cursor[base + i] = run;
            run += local[i];
        }
    }
    if (t == 1023) rowstart[NN] = NT;
    if (t <= NG) {
        int lo = 0, hi = NN;
        while (lo < hi) {
            int mid = (lo + hi) >> 1;
            if (batch[mid] < t) lo = mid + 1; else hi = mid;
        }
        gstart[t] = lo;
    }
}

// ---------- D3: CSR scatter ----------
__global__ void k_scatter(const int* __restrict__ ei, int* __restrict__ cursor,
                          int* __restrict__ csr_src) {
    int t = blockIdx.x * blockDim.x + threadIdx.x;
    if (t >= NT) return;
    int d = edst(ei, t), s = esrc(ei, t);
    int pos = atomicAdd(&cursor[d], 1);
    csr_src[pos] = s;
}

// ---------- D4: layer-1 softmax+aggregate, dual-node waves ----------
// 8 nodes/block (4 waves x 2 nodes). Octet layout lane=(e8,c8); c8 = head.
// Both nodes' edge loops fused -> 4 gathers + 4 logit loads in flight per iteration.
__global__ void k_l1(const int* __restrict__ rowstart, const int* __restrict__ csr_src,
                     const float* __restrict__ al_s, const float* __restrict__ al_d,
                     const unsigned short* __restrict__ h1bf, const float* __restrict__ b1,
                     const float* __restrict__ a2ps, const float* __restrict__ a2pd,
                     unsigned short* __restrict__ o1bf, float* __restrict__ al_s2,
                     float* __restrict__ al_d2) {
    int w = threadIdx.x >> 6, lane = threadIdx.x & 63;
    int e8 = lane >> 3, c8 = lane & 7;
    int nA = blockIdx.x * 8 + w * 2;
    int nB = nA + 1;
    int stA = rowstart[nA], degA = rowstart[nA + 1] - stA;
    int stB = rowstart[nB], degB = rowstart[nB + 1] - stB;
    float aldA = al_d[nA * 8 + c8], aldB = al_d[nB * 8 + c8];
    float accA[8] = {0.f, 0.f, 0.f, 0.f, 0.f, 0.f, 0.f, 0.f};
    float accB[8] = {0.f, 0.f, 0.f, 0.f, 0.f, 0.f, 0.f, 0.f};
    float dsA = 0.f, dsB = 0.f;
    int dmax = degA > degB ? degA : degB;
    for (int base = 0; base < dmax; base += 16) {
        int s0 = base + e8, s1 = base + 8 + e8;
        int iA0 = csr_src[stA + (s0 < degA ? s0 : 0)];
        int iA1 = csr_src[stA + (s1 < degA ? s1 : 0)];
        int iB0 = csr_src[stB + (s0 < degB ? s0 : 0)];
        int iB1 = csr_src[stB + (s1 < degB ? s1 : 0)];
        float eA0 = (s0 < degA) ? __expf(lrelu(al_s[iA0 * 8 + c8] + aldA)) : 0.f;
        float eA1 = (s1 < degA) ? __expf(lrelu(al_s[iA1 * 8 + c8] + aldA)) : 0.f;
        float eB0 = (s0 < degB) ? __expf(lrelu(al_s[iB0 * 8 + c8] + aldB)) : 0.f;
        float eB1 = (s1 < degB) ? __expf(lrelu(al_s[iB1 * 8 + c8] + aldB)) : 0.f;
        uint4 hA0 = *(const uint4*)(h1bf + iA0 * 64 + c8 * 8);
        uint4 hA1 = *(const uint4*)(h1bf + iA1 * 64 + c8 * 8);
        uint4 hB0 = *(const uint4*)(h1bf + iB0 * 64 + c8 * 8);
        uint4 hB1 = *(const uint4*)(h1bf + iB1 * 64 + c8 * 8);
        dsA += eA0 + eA1;
        dsB += eB0 + eB1;
        ACC8(accA, eA0, hA0);
        ACC8(accA, eA1, hA1);
        ACC8(accB, eB0, hB0);
        ACC8(accB, eB1, hB1);
    }
    // reduce across the 8 edge slots (lane bits 3..5)
#pragma unroll
    for (int o = 32; o >= 8; o >>= 1) {
#pragma unroll
        for (int k = 0; k < 8; ++k) {
            accA[k] += __shfl_xor(accA[k], o, 64);
            accB[k] += __shfl_xor(accB[k], o, 64);
        }
        dsA += __shfl_xor(dsA, o, 64);
        dsB += __shfl_xor(dsB, o, 64);
    }
    if (e8 == 0) {   // lanes 0..7: finalize head c8's 8 channels for both nodes
        float invA = 1.f / dsA, invB = 1.f / dsB;
        const float* bp = b1 + c8 * 8;
        const float* asp = a2ps + c8 * 8;
        const float* adp = a2pd + c8 * 8;
        float vA[8], vB[8];
#pragma unroll
        for (int k = 0; k < 8; ++k) {
            vA[k] = elu1(accA[k] * invA + bp[k]);
            vB[k] = elu1(accB[k] * invB + bp[k]);
        }
        uint4 pkA, pkB;
        pkA.x = (unsigned)f2bf(vA[0]) | ((unsigned)f2bf(vA[1]) << 16);
        pkA.y = (unsigned)f2bf(vA[2]) | ((unsigned)f2bf(vA[3]) << 16);
        pkA.z = (unsigned)f2bf(vA[4]) | ((unsigned)f2bf(vA[5]) << 16);
        pkA.w = (unsigned)f2bf(vA[6]) | ((unsigned)f2bf(vA[7]) << 16);
        pkB.x = (unsigned)f2bf(vB[0]) | ((unsigned)f2bf(vB[1]) << 16);
        pkB.y = (unsigned)f2bf(vB[2]) | ((unsigned)f2bf(vB[3]) << 16);
        pkB.z = (unsigned)f2bf(vB[4]) | ((unsigned)f2bf(vB[5]) << 16);
        pkB.w = (unsigned)f2bf(vB[6]) | ((unsigned)f2bf(vB[7]) << 16);
        *(uint4*)(o1bf + nA * 64 + c8 * 8) = pkA;
        *(uint4*)(o1bf + nB * 64 + c8 * 8) = pkB;
        float psA = 0.f, pdA = 0.f, psB = 0.f, pdB = 0.f;
#pragma unroll
        for (int k = 0; k < 8; ++k) {
            psA = fmaf(vA[k], asp[k], psA);
            pdA = fmaf(vA[k], adp[k], pdA);
            psB = fmaf(vB[k], asp[k], psB);
            pdB = fmaf(vB[k], adp[k], pdB);
        }
        for (int o = 4; o >= 1; o >>= 1) {
            psA += __shfl_xor(psA, o, 8);
            pdA += __shfl_xor(pdA, o, 8);
            psB += __shfl_xor(psB, o, 8);
            pdB += __shfl_xor(pdB, o, 8);
        }
        if (c8 == 0) {
            al_s2[nA] = psA; al_d2[nA] = pdA;
            al_s2[nB] = psB; al_d2[nB] = pdB;
        }
    }
}

// ---------- D5: layer-2 softmax-agg (dual-node fused loop) + MFMA @W2 + elu + pool ----------
// 16 nodes/block, 512 threads (8 waves). Phase A: wave w handles nodes w*2,w*2+1 jointly.
// Phase B: MFMA (A from LDS, B from W2bfT), elu, graph-masked pool -> atomics into sums.
__global__ void k_l2gemm(const int* __restrict__ rowstart, const int* __restrict__ csr_src,
                         const float* __restrict__ al_s2, const float* __restrict__ al_d2,
                         const unsigned short* __restrict__ o1bf,
                         const unsigned short* __restrict__ W2bfT,
                         const float* __restrict__ b2, const int* __restrict__ batch,
                         float* __restrict__ sums) {
    __shared__ unsigned short lagg[16][72];   // padded rows: 144B stride
    int n0 = blockIdx.x * 16;
    int w = threadIdx.x >> 6, lane = threadIdx.x & 63;
    int e8 = lane >> 3, c8 = lane & 7;
    int rA = w * 2, rB = rA + 1;
    int nA = n0 + rA, nB = n0 + rB;
    int stA = rowstart[nA], degA = rowstart[nA + 1] - stA;
    int stB = rowstart[nB], degB = rowstart[nB + 1] - stB;
    float aldA = al_d2[nA], aldB = al_d2[nB];
    float accA[8] = {0.f, 0.f, 0.f, 0.f, 0.f, 0.f, 0.f, 0.f};
    float accB[8] = {0.f, 0.f, 0.f, 0.f, 0.f, 0.f, 0.f, 0.f};
    float dsA = 0.f, dsB = 0.f;
    int dmax = degA > degB ? degA : degB;
    for (int base = 0; base < dmax; base += 16) {
        int s0 = base + e8, s1 = base + 8 + e8;
        int iA0 = csr_src[stA + (s0 < degA ? s0 : 0)];
        int iA1 = csr_src[stA + (s1 < degA ? s1 : 0)];
        int iB0 = csr_src[stB + (s0 < degB ? s0 : 0)];
        int iB1 = csr_src[stB + (s1 < degB ? s1 : 0)];
        float eA0 = (s0 < degA) ? __expf(lrelu(al_s2[iA0] + aldA)) : 0.f;
        float eA1 = (s1 < degA) ? __expf(lrelu(al_s2[iA1] + aldA)) : 0.f;
        float eB0 = (s0 < degB) ? __expf(lrelu(al_s2[iB0] + aldB)) : 0.f;
        float eB1 = (s1 < degB) ? __expf(lrelu(al_s2[iB1] + aldB)) : 0.f;
        uint4 hA0 = *(const uint4*)(o1bf + iA0 * 64 + c8 * 8);
        uint4 hA1 = *(const uint4*)(o1bf + iA1 * 64 + c8 * 8);
        uint4 hB0 = *(const uint4*)(o1bf + iB0 * 64 + c8 * 8);
        uint4 hB1 = *(const uint4*)(o1bf + iB1 * 64 + c8 * 8);
        dsA += eA0 + eA1;
        dsB += eB0 + eB1;
        ACC8(accA, eA0, hA0);
        ACC8(accA, eA1, hA1);
        ACC8(accB, eB0, hB0);
        ACC8(accB, eB1, hB1);
    }
#pragma unroll
    for (int o = 32; o >= 8; o >>= 1) {
#pragma unroll
        for (int k = 0; k < 8; ++k) {
            accA[k] += __shfl_xor(accA[k], o, 64);
            accB[k] += __shfl_xor(accB[k], o, 64);
        }
        dsA += __shfl_xor(dsA, o, 64);
        dsB += __shfl_xor(dsB, o, 64);
    }
    if (e8 == 0) {   // lanes 0..7 pack channels c8*8..+7 for both nodes
        float invA = 1.f / dsA, invB = 1.f / dsB;
        uint4 pkA, pkB;
        pkA.x = (unsigned)f2bf(accA[0] * invA) | ((unsigned)f2bf(accA[1] * invA) << 16);
        pkA.y = (unsigned)f2bf(accA[2] * invA) | ((unsigned)f2bf(accA[3] * invA) << 16);
        pkA.z = (unsigned)f2bf(accA[4] * invA) | ((unsigned)f2bf(accA[5] * invA) << 16);
        pkA.w = (unsigned)f2bf(accA[6] * invA) | ((unsigned)f2bf(accA[7] * invA) << 16);
        pkB.x = (unsigned)f2bf(accB[0] * invB) | ((unsigned)f2bf(accB[1] * invB) << 16);
        pkB.y = (unsigned)f2bf(accB[2] * invB) | ((unsigned)f2bf(accB[3] * invB) << 16);
        pkB.z = (unsigned)f2bf(accB[4] * invB) | ((unsigned)f2bf(accB[5] * invB) << 16);
        pkB.w = (unsigned)f2bf(accB[6] * invB) | ((unsigned)f2bf(accB[7] * invB) << 16);
        *(uint4*)&lagg[rA][c8 * 8] = pkA;
        *(uint4*)&lagg[rB][c8 * 8] = pkB;
    }
    __syncthreads();
    // phase B: A[m=lane&15][k=quad*8+j] from LDS; B[k][n=lane&15] from W2bfT (n-major).
    int mcol = lane & 15;
    int q = lane >> 4;
    short8 a0 = *(const short8*)&lagg[mcol][q * 8];
    short8 a1 = *(const short8*)&lagg[mcol][32 + q * 8];
    int gmin = batch[n0], gmax = batch[n0 + 15];
    int batchq[4];
#pragma unroll
    for (int r = 0; r < 4; ++r) batchq[r] = batch[n0 + q * 4 + r];
#pragma unroll
    for (int t = 0; t < 4; ++t) {
        int c = w * 64 + t * 16 + mcol;
        const unsigned short* bp = W2bfT + c * 64 + q * 8;
        short8 b0 = *(const short8*)bp;
        short8 b1v = *(const short8*)(bp + 32);
        float4v acc = {0.f, 0.f, 0.f, 0.f};
        acc = __builtin_amdgcn_mfma_f32_16x16x32_bf16(a0, b0, acc, 0, 0, 0);
        acc = __builtin_amdgcn_mfma_f32_16x16x32_bf16(a1, b1v, acc, 0, 0, 0);
        float bias = b2[c];
        float val[4];
#pragma unroll
        for (int r = 0; r < 4; ++r) val[r] = elu1(acc[r] + bias);
        for (int g = gmin; g <= gmax; ++g) {
            float s = 0.f;
#pragma unroll
            for (int r = 0; r < 4; ++r) s += (batchq[r] == g) ? val[r] : 0.f;
            s += __shfl_xor(s, 16, 64);   // reduce across the 4 quads
            s += __shfl_xor(s, 32, 64);
            if (q == 0) atomicAdd(&sums[g * 512 + c], s);
        }
    }
}

// ---------- D6: final GEMM: out[g][j] = (sums[g] @ Wo[:,j]) / cnt[g] + bo[j] ----------
__global__ void k_final(const float* __restrict__ sums, const int* __restrict__ gstart,
                        const float* __restrict__ Wo, const float* __restrict__ bo,
                        float* __restrict__ out) {
    __shared__ float sp[512];
    int g = blockIdx.x >> 3;
    int j = (blockIdx.x & 7) * 64 + threadIdx.x;  // 64 threads
    for (int k = threadIdx.x; k < 512; k += 64) sp[k] = sums[g * 512 + k];
    __syncthreads();
    float c = (float)(gstart[g + 1] - gstart[g]);
    float inv = 1.f / (c > 0.f ? c : 1.f);
    float acc = 0.f;
    for (int k = 0; k < 512; ++k) acc = fmaf(sp[k], Wo[k * 512 + j], acc);
    out[g * 512 + j] = fmaf(acc, inv, bo[j]);
}

extern "C" void kernel_launch(void* const* d_in, const int* in_sizes, int n_in,
                              void* d_out, int out_size, void* d_ws, size_t ws_size,
                              hipStream_t stream) {
    const float* x     = (const float*)d_in[0];
    const int*   ei    = (const int*)d_in[1];    // [2, NE]
    const int*   batch = (const int*)d_in[2];    // [NN] sorted
    const float* W1    = (const float*)d_in[3];
    const float* as1   = (const float*)d_in[4];
    const float* ad1   = (const float*)d_in[5];
    const float* b1    = (const float*)d_in[6];
    const float* W2    = (const float*)d_in[7];
    const float* as2   = (const float*)d_in[8];
    const float* ad2   = (const float*)d_in[9];
    const float* b2    = (const float*)d_in[10];
    const float* Wo    = (const float*)d_in[11];
    const float* bo    = (const float*)d_in[12];
    float* out = (float*)d_out;

    // ---- workspace arena (4-byte units) ----
    float* w = (float*)d_ws;
    unsigned short* h1bf  = (unsigned short*)(w + 0);        // 640,000 units
    float* al_s1 = w + 640000;     // 160,000
    float* al_d1 = w + 800000;     // 160,000
    unsigned short* o1bf  = (unsigned short*)(w + 960000);   // 640,000 units (byte 3,840,000: 16B aligned)
    unsigned short* W2bfT = (unsigned short*)(w + 1600000);  // 16,384 units (byte 6,400,000: 16B aligned)
    float* a2ps  = w + 1616384;    // 64
    float* a2pd  = w + 1616448;    // 64
    float* al_s2 = w + 1616512;    // 20,000
    float* al_d2 = w + 1636512;    // 20,000
    int*   rowstart = (int*)(w + 1656512);   // 20,001
    int*   cursor   = (int*)(w + 1676516);   // 20,000
    int*   csr_src  = (int*)(w + 1696516);   // 340,000
    int*   gstart   = (int*)(w + 2036516);   // 65
    float* sums     = w + 2036584;           // 32,768 (byte 8,146,336: 16B aligned; zeroed in k_scan)
    // ---- zero-initialized region ----
    int*   deg      = (int*)(w + 2069352);   // 20,000
    // end: 2,089,352 units ≈ 8.4 MB

    hipMemsetAsync(w + 2069352, 0, (size_t)20000 * 4, stream);

    k_prep   <<<HB + CB + AB + NN / 4, 256, 0, stream>>>(ei, deg, W2, W2bfT, as2, ad2,
                                                         a2ps, a2pd, x, W1, as1, ad1,
                                                         h1bf, al_s1, al_d1);
    k_scan   <<<1, 1024, 0, stream>>>(deg, batch, rowstart, cursor, gstart, sums);
    k_scatter<<<HB, 256, 0, stream>>>(ei, cursor, csr_src);
    k_l1     <<<NN / 8, 256, 0, stream>>>(rowstart, csr_src, al_s1, al_d1, h1bf, b1,
                                          a2ps, a2pd, o1bf, al_s2, al_d2);
    k_l2gemm <<<NN / 16, 512, 0, stream>>>(rowstart, csr_src, al_s2, al_d2, o1bf,
                                           W2bfT, b2, batch, sums);
    k_final  <<<NG * 8, 64, 0, stream>>>(sums, gstart, Wo, bo, out);
}

// Round 17
// 197.158 us; speedup vs baseline: 1.0190x; 1.0190x over previous
//
#include <hip/hip_runtime.h>
#include <math.h>

#define NN 20000      // nodes
#define NE 320000     // edges (without self loops)
#define NT 340000     // edges + self loops
#define NG 64         // graphs
#define HB 1329       // (NT+255)/256 hist/scatter blocks
#define CB 8          // W2->bf16 LDS-transpose blocks (512/64)
#define AB 2          // a2p GEMV blocks

using short8  = __attribute__((ext_vector_type(8))) short;   // 8 x bf16 (4 VGPRs)
using float4v = __attribute__((ext_vector_type(4))) float;   // MFMA accumulator

__device__ __forceinline__ float lrelu(float v) { return v > 0.f ? v : 0.2f * v; }
__device__ __forceinline__ float elu1(float v)  { return v > 0.f ? v : (expf(v) - 1.f); }
__device__ __forceinline__ float bflo(unsigned u) { return __uint_as_float(u << 16); }
__device__ __forceinline__ float bfhi(unsigned u) { return __uint_as_float(u & 0xFFFF0000u); }
__device__ __forceinline__ unsigned short f2bf(float f) {
    unsigned u = __float_as_uint(f);
    u += 0x7FFFu + ((u >> 16) & 1u);   // round to nearest even
    return (unsigned short)(u >> 16);
}
__device__ __forceinline__ float bf2f(unsigned short s) {
    return __uint_as_float(((unsigned)s) << 16);
}

#define ACC8(ex, hv) \
    acc[0] = fmaf(ex, bflo(hv.x), acc[0]); \
    acc[1] = fmaf(ex, bfhi(hv.x), acc[1]); \
    acc[2] = fmaf(ex, bflo(hv.y), acc[2]); \
    acc[3] = fmaf(ex, bfhi(hv.y), acc[3]); \
    acc[4] = fmaf(ex, bflo(hv.z), acc[4]); \
    acc[5] = fmaf(ex, bfhi(hv.z), acc[5]); \
    acc[6] = fmaf(ex, bflo(hv.w), acc[6]); \
    acc[7] = fmaf(ex, bfhi(hv.w), acc[7]);

__device__ __forceinline__ int esrc(const int* ei, int e) { return e < NE ? ei[e] : (e - NE); }
__device__ __forceinline__ int edst(const int* ei, int e) { return e < NE ? ei[NE + e] : (e - NE); }

// ---------- D1: fused prep (all grid-parallel; no serial tail) ----------
__global__ void k_prep(const int* __restrict__ ei, int* __restrict__ deg,
                       const float* __restrict__ W2, unsigned short* __restrict__ W2bfT,
                       const float* __restrict__ as2, const float* __restrict__ ad2,
                       float* __restrict__ a2ps, float* __restrict__ a2pd,
                       const float* __restrict__ x, const float* __restrict__ W1,
                       const float* __restrict__ as1, const float* __restrict__ ad1,
                       unsigned short* __restrict__ h1bf, float* __restrict__ al_s,
                       float* __restrict__ al_d) {
    int tid = threadIdx.x;
    int b = blockIdx.x;
    if (b < HB) {
        int t = b * 256 + tid;
        if (t < NE) atomicAdd(&deg[ei[NE + t]], 1);
        return;
    }
    if (b < HB + CB) {
        // coalesced W2 transpose via LDS tile: 64 k-rows x 64 n-cols
        __shared__ unsigned short tile[64][65];
        int n0t = (b - HB) * 64;
#pragma unroll
        for (int r = 0; r < 16; ++r) {
            int k = r * 4 + (tid >> 6);
            int nl = tid & 63;
            tile[k][nl] = f2bf(W2[k * 512 + n0t + nl]);
        }
        __syncthreads();
#pragma unroll
        for (int r = 0; r < 16; ++r) {
            int nl = r * 4 + (tid >> 6);
            int k = tid & 63;
            W2bfT[(n0t + nl) * 64 + k] = tile[k][nl];
        }
        return;
    }
    if (b < HB + CB + AB) {
        // a2p[k] = sum_j W2[k][j] * a[j]   (64x512 GEMV)
        __shared__ float pp[4][64];
        const float* av = (b == HB + CB) ? as2 : ad2;
        float* outp     = (b == HB + CB) ? a2ps : a2pd;
        int k = tid & 63, seg = tid >> 6;
        float s = 0.f;
        for (int j = seg * 128; j < seg * 128 + 128; ++j)
            s = fmaf(W2[k * 512 + j], av[j], s);
        pp[seg][k] = s;
        __syncthreads();
        if (tid < 64) outp[tid] = pp[0][tid] + pp[1][tid] + pp[2][tid] + pp[3][tid];
        return;
    }
    int n = (b - HB - CB - AB) * 4 + (tid >> 6);
    int j = tid & 63;
    float x0 = x[n * 3 + 0], x1 = x[n * 3 + 1], x2 = x[n * 3 + 2];
    float v = fmaf(x0, W1[j], fmaf(x1, W1[64 + j], x2 * W1[128 + j]));
    h1bf[n * 64 + j] = f2bf(v);
    float ps = v * as1[j];
    float pd = v * ad1[j];
    for (int o = 4; o >= 1; o >>= 1) {
        ps += __shfl_xor(ps, o, 8);
        pd += __shfl_xor(pd, o, 8);
    }
    if ((j & 7) == 0) {
        al_s[n * 8 + (j >> 3)] = ps;
        al_d[n * 8 + (j >> 3)] = pd;
    }
}

// ---------- D2: single-block scan (plain cached loads, L2-hot) + sums zeroing ----------
__global__ void k_scan(const int* __restrict__ deg, const int* __restrict__ batch,
                       int* __restrict__ rowstart, int* __restrict__ cursor,
                       int* __restrict__ gstart, float* __restrict__ sums) {
    __shared__ int part[1024];
    int t = threadIdx.x;
    // zero sums (32768 floats; 8 float4 per thread)
    {
        float4* sp = (float4*)sums;
#pragma unroll
        for (int i = 0; i < 8; ++i)
            sp[t * 8 + i] = make_float4(0.f, 0.f, 0.f, 0.f);
    }
    int base = t * 20;
    int local[20];
    int s = 0;
    if (base < NN) {
#pragma unroll
        for (int i = 0; i < 20; ++i) { local[i] = deg[base + i] + 1; s += local[i]; }
    }
    part[t] = s;
    __syncthreads();
    for (int o = 1; o < 1024; o <<= 1) {
        int v = (t >= o) ? part[t - o] : 0;
        __syncthreads();
        part[t] += v;
        __syncthreads();
    }
    if (base < NN) {
        int run = (t == 0) ? 0 : part[t - 1];
#pragma unroll
        for (int i = 0; i < 20; ++i) {
            rowstart[base + i] = run;
            cursor[base + i] = run;
            run += local[i];
        }
    }
    if (t == 1023) rowstart[NN] = NT;
    if (t <= NG) {
        int lo = 0, hi = NN;
        while (lo < hi) {
            int mid = (lo + hi) >> 1;
            if (batch[mid] < t) lo = mid + 1; else hi = mid;
        }
        gstart[t] = lo;
    }
}

// ---------- D3: CSR scatter ----------
__global__ void k_scatter(const int* __restrict__ ei, int* __restrict__ cursor,
                          int* __restrict__ csr_src) {
    int t = blockIdx.x * blockDim.x + threadIdx.x;
    if (t >= NT) return;
    int d = edst(ei, t), s = esrc(ei, t);
    int pos = atomicAdd(&cursor[d], 1);
    csr_src[pos] = s;
}

// ---------- D4: fused layer-1 softmax+aggregate (single pass, no max-sub) + elu; l2 logits ----
// 4 nodes/block (1 wave each). Octet layout: lane=(e8,c8); c8 = head. Each lane computes its
// edge's ex inline (logits O(+-5): exp safe without max shift), accumulates dsum + acc[8];
// one shuffle tree reduces all 9 values over the e8 bits.
__global__ void k_l1(const int* __restrict__ rowstart, const int* __restrict__ csr_src,
                     const float* __restrict__ al_s, const float* __restrict__ al_d,
                     const unsigned short* __restrict__ h1bf, const float* __restrict__ b1,
                     const float* __restrict__ a2ps, const float* __restrict__ a2pd,
                     unsigned short* __restrict__ o1bf, float* __restrict__ al_s2,
                     float* __restrict__ al_d2) {
    int nb = threadIdx.x >> 6;
    int n = blockIdx.x * 4 + nb;
    int lane = threadIdx.x & 63;
    int e8 = lane >> 3, c8 = lane & 7;   // edge slot, head
    int start = rowstart[n], end = rowstart[n + 1];
    int deg = end - start;
    float ald = al_d[n * 8 + c8];
    float acc[8] = {0.f, 0.f, 0.f, 0.f, 0.f, 0.f, 0.f, 0.f};
    float dsum = 0.f;
    for (int base = 0; base < deg; base += 16) {
        int slotA = base + e8;
        int slotB = base + 8 + e8;
        int sA = csr_src[start + (slotA < deg ? slotA : 0)];
        int sB = csr_src[start + (slotB < deg ? slotB : 0)];
        float exA = 0.f, exB = 0.f;
        if (slotA < deg) exA = __expf(lrelu(al_s[sA * 8 + c8] + ald));
        if (slotB < deg) exB = __expf(lrelu(al_s[sB * 8 + c8] + ald));
        dsum += exA + exB;
        uint4 hA = *(const uint4*)(h1bf + sA * 64 + c8 * 8);
        uint4 hB = *(const uint4*)(h1bf + sB * 64 + c8 * 8);
        ACC8(exA, hA);
        ACC8(exB, hB);
    }
    // reduce acc[8] + dsum across the 8 edge slots (lane bits 3..5)
#pragma unroll
    for (int o = 32; o >= 8; o >>= 1) {
#pragma unroll
        for (int k = 0; k < 8; ++k) acc[k] += __shfl_xor(acc[k], o, 64);
        dsum += __shfl_xor(dsum, o, 64);
    }
    if (e8 == 0) {   // lanes 0..7: finalize head c8's 8 channels
        float inv = 1.f / dsum;
        const float* bp = b1 + c8 * 8;
        float v[8];
#pragma unroll
        for (int k = 0; k < 8; ++k) v[k] = elu1(acc[k] * inv + bp[k]);
        uint4 pk;
        pk.x = (unsigned)f2bf(v[0]) | ((unsigned)f2bf(v[1]) << 16);
        pk.y = (unsigned)f2bf(v[2]) | ((unsigned)f2bf(v[3]) << 16);
        pk.z = (unsigned)f2bf(v[4]) | ((unsigned)f2bf(v[5]) << 16);
        pk.w = (unsigned)f2bf(v[6]) | ((unsigned)f2bf(v[7]) << 16);
        *(uint4*)(o1bf + n * 64 + c8 * 8) = pk;
        float ps = 0.f, pd = 0.f;
        const float* asp = a2ps + c8 * 8;
        const float* adp = a2pd + c8 * 8;
#pragma unroll
        for (int k = 0; k < 8; ++k) {
            ps = fmaf(v[k], asp[k], ps);
            pd = fmaf(v[k], adp[k], pd);
        }
        for (int o = 4; o >= 1; o >>= 1) {
            ps += __shfl_xor(ps, o, 8);
            pd += __shfl_xor(pd, o, 8);
        }
        if (c8 == 0) { al_s2[n] = ps; al_d2[n] = pd; }
    }
}

// ---------- D5: fused layer-2 softmax-agg (single pass, octet) + MFMA @W2 + elu + pool ------
// 16 nodes/block, 512 threads (8 waves). Phase A: wave w handles nodes w*2,w*2+1, ex inline.
// Phase B: MFMA (A from LDS, B from W2bfT), elu, graph-masked pool -> atomics into sums.
__global__ void k_l2gemm(const int* __restrict__ rowstart, const int* __restrict__ csr_src,
                         const float* __restrict__ al_s2, const float* __restrict__ al_d2,
                         const unsigned short* __restrict__ o1bf,
                         const unsigned short* __restrict__ W2bfT,
                         const float* __restrict__ b2, const int* __restrict__ batch,
                         float* __restrict__ sums) {
    __shared__ unsigned short lagg[16][72];   // padded rows: 144B stride
    int n0 = blockIdx.x * 16;
    int w = threadIdx.x >> 6, lane = threadIdx.x & 63;
    int e8 = lane >> 3, c8 = lane & 7;
#pragma unroll
    for (int i = 0; i < 2; ++i) {
        int r = w * 2 + i;
        int n = n0 + r;
        float ald = al_d2[n];
        int start = rowstart[n], end = rowstart[n + 1];
        int deg = end - start;
        float acc[8] = {0.f, 0.f, 0.f, 0.f, 0.f, 0.f, 0.f, 0.f};
        float dsum = 0.f;
        for (int base = 0; base < deg; base += 16) {
            int slotA = base + e8;
            int slotB = base + 8 + e8;
            int sA = csr_src[start + (slotA < deg ? slotA : 0)];
            int sB = csr_src[start + (slotB < deg ? slotB : 0)];
            float exA = 0.f, exB = 0.f;
            if (slotA < deg) exA = __expf(lrelu(al_s2[sA] + ald));
            if (slotB < deg) exB = __expf(lrelu(al_s2[sB] + ald));
            dsum += exA + exB;
            uint4 hA = *(const uint4*)(o1bf + sA * 64 + c8 * 8);
            uint4 hB = *(const uint4*)(o1bf + sB * 64 + c8 * 8);
            ACC8(exA, hA);
            ACC8(exB, hB);
        }
#pragma unroll
        for (int o = 32; o >= 8; o >>= 1) {
#pragma unroll
            for (int k = 0; k < 8; ++k) acc[k] += __shfl_xor(acc[k], o, 64);
            dsum += __shfl_xor(dsum, o, 64);
        }
        if (e8 == 0) {   // lanes 0..7 pack channels c8*8..+7
            float inv = 1.f / dsum;
            uint4 pk;
            pk.x = (unsigned)f2bf(acc[0] * inv) | ((unsigned)f2bf(acc[1] * inv) << 16);
            pk.y = (unsigned)f2bf(acc[2] * inv) | ((unsigned)f2bf(acc[3] * inv) << 16);
            pk.z = (unsigned)f2bf(acc[4] * inv) | ((unsigned)f2bf(acc[5] * inv) << 16);
            pk.w = (unsigned)f2bf(acc[6] * inv) | ((unsigned)f2bf(acc[7] * inv) << 16);
            *(uint4*)&lagg[r][c8 * 8] = pk;
        }
    }
    __syncthreads();
    // phase B: A[m=lane&15][k=quad*8+j] from LDS; B[k][n=lane&15] from W2bfT (n-major).
    int mcol = lane & 15;
    int q = lane >> 4;
    short8 a0 = *(const short8*)&lagg[mcol][q * 8];
    short8 a1 = *(const short8*)&lagg[mcol][32 + q * 8];
    int gmin = batch[n0], gmax = batch[n0 + 15];
    int batchq[4];
#pragma unroll
    for (int r = 0; r < 4; ++r) batchq[r] = batch[n0 + q * 4 + r];
#pragma unroll
    for (int t = 0; t < 4; ++t) {
        int c = w * 64 + t * 16 + mcol;
        const unsigned short* bp = W2bfT + c * 64 + q * 8;
        short8 b0 = *(const short8*)bp;
        short8 b1v = *(const short8*)(bp + 32);
        float4v acc = {0.f, 0.f, 0.f, 0.f};
        acc = __builtin_amdgcn_mfma_f32_16x16x32_bf16(a0, b0, acc, 0, 0, 0);
        acc = __builtin_amdgcn_mfma_f32_16x16x32_bf16(a1, b1v, acc, 0, 0, 0);
        float bias = b2[c];
        float val[4];
#pragma unroll
        for (int r = 0; r < 4; ++r) val[r] = elu1(acc[r] + bias);
        for (int g = gmin; g <= gmax; ++g) {
            float s = 0.f;
#pragma unroll
            for (int r = 0; r < 4; ++r) s += (batchq[r] == g) ? val[r] : 0.f;
            s += __shfl_xor(s, 16, 64);   // reduce across the 4 quads
            s += __shfl_xor(s, 32, 64);
            if (q == 0) atomicAdd(&sums[g * 512 + c], s);
        }
    }
}

// ---------- D6: final GEMM: out[g][j] = (sums[g] @ Wo[:,j]) / cnt[g] + bo[j] ----------
__global__ void k_final(const float* __restrict__ sums, const int* __restrict__ gstart,
                        const float* __restrict__ Wo, const float* __restrict__ bo,
                        float* __restrict__ out) {
    __shared__ float sp[512];
    int g = blockIdx.x >> 3;
    int j = (blockIdx.x & 7) * 64 + threadIdx.x;  // 64 threads
    for (int k = threadIdx.x; k < 512; k += 64) sp[k] = sums[g * 512 + k];
    __syncthreads();
    float c = (float)(gstart[g + 1] - gstart[g]);
    float inv = 1.f / (c > 0.f ? c : 1.f);
    float acc = 0.f;
    for (int k = 0; k < 512; ++k) acc = fmaf(sp[k], Wo[k * 512 + j], acc);
    out[g * 512 + j] = fmaf(acc, inv, bo[j]);
}

extern "C" void kernel_launch(void* const* d_in, const int* in_sizes, int n_in,
                              void* d_out, int out_size, void* d_ws, size_t ws_size,
                              hipStream_t stream) {
    const float* x     = (const float*)d_in[0];
    const int*   ei    = (const int*)d_in[1];    // [2, NE]
    const int*   batch = (const int*)d_in[2];    // [NN] sorted
    const float* W1    = (const float*)d_in[3];
    const float* as1   = (const float*)d_in[4];
    const float* ad1   = (const float*)d_in[5];
    const float* b1    = (const float*)d_in[6];
    const float* W2    = (const float*)d_in[7];
    const float* as2   = (const float*)d_in[8];
    const float* ad2   = (const float*)d_in[9];
    const float* b2    = (const float*)d_in[10];
    const float* Wo    = (const float*)d_in[11];
    const float* bo    = (const float*)d_in[12];
    float* out = (float*)d_out;

    // ---- workspace arena (4-byte units) ----
    float* w = (float*)d_ws;
    unsigned short* h1bf  = (unsigned short*)(w + 0);        // 640,000 units
    float* al_s1 = w + 640000;     // 160,000
    float* al_d1 = w + 800000;     // 160,000
    unsigned short* o1bf  = (unsigned short*)(w + 960000);   // 640,000 units (byte 3,840,000: 16B aligned)
    unsigned short* W2bfT = (unsigned short*)(w + 1600000);  // 16,384 units (byte 6,400,000: 16B aligned)
    float* a2ps  = w + 1616384;    // 64
    float* a2pd  = w + 1616448;    // 64
    float* al_s2 = w + 1616512;    // 20,000
    float* al_d2 = w + 1636512;    // 20,000
    int*   rowstart = (int*)(w + 1656512);   // 20,001
    int*   cursor   = (int*)(w + 1676516);   // 20,000
    int*   csr_src  = (int*)(w + 1696516);   // 340,000
    int*   gstart   = (int*)(w + 2036516);   // 65
    float* sums     = w + 2036584;           // 32,768 (byte 8,146,336: 16B aligned; zeroed in k_scan)
    // ---- zero-initialized region ----
    int*   deg      = (int*)(w + 2069352);   // 20,000
    // end: 2,089,352 units ≈ 8.4 MB

    hipMemsetAsync(w + 2069352, 0, (size_t)20000 * 4, stream);

    k_prep   <<<HB + CB + AB + NN / 4, 256, 0, stream>>>(ei, deg, W2, W2bfT, as2, ad2,
                                                         a2ps, a2pd, x, W1, as1, ad1,
                                                         h1bf, al_s1, al_d1);
    k_scan   <<<1, 1024, 0, stream>>>(deg, batch, rowstart, cursor, gstart, sums);
    k_scatter<<<HB, 256, 0, stream>>>(ei, cursor, csr_src);
    k_l1     <<<NN / 4, 256, 0, stream>>>(rowstart, csr_src, al_s1, al_d1, h1bf, b1,
                                          a2ps, a2pd, o1bf, al_s2, al_d2);
    k_l2gemm <<<NN / 16, 512, 0, stream>>>(rowstart, csr_src, al_s2, al_d2, o1bf,
                                           W2bfT, b2, batch, sums);
    k_final  <<<NG * 8, 64, 0, stream>>>(sums, gstart, Wo, bo, out);
}